// Round 2
// baseline (1238.938 us; speedup 1.0000x reference)
//
#include <hip/hip_runtime.h>

#define TB 512

constexpr int BHC = 32;     // B*H
constexpr int LEN = 8192;   // L
constexpr int DD  = 64;     // d
constexpr int RR  = 266;    // num_rows
constexpr int RP  = 272;    // padded to 16*17
constexpr float EPSF = 1e-3f;

// ---------------------------------------------------------------------------
// Kernel 1: per (bh, 1024-row chunk): kp = relu(K @ P^T)+eps, accumulate
//           KV[r][d] += kp[l][r]*V[l][d] and ksum[r] += kp[l][r]; atomicAdd out.
// LDS: proj (swizzled f4) 69632 + k tile 8192 + kp 34944 + v tile 8192 = 120960 B
// ---------------------------------------------------------------------------
__global__ __launch_bounds__(TB, 1) void perf_kv_kernel(
    const float* __restrict__ kin, const float* __restrict__ vin,
    const float* __restrict__ proj,
    float* __restrict__ kv_ws, float* __restrict__ ksum_ws)
{
  __shared__ __align__(16) float4 proj4[RP * 16];   // [r][c4] at slot r*16 + (c4 ^ (r&15))
  __shared__ __align__(16) float4 k4[32 * 16];      // [l][c4] at slot l*16 + (c4 ^ (l&15))
  __shared__ float kp[32 * 273];                    // [l][r], stride 273 (bank-spread)
  __shared__ __align__(16) float vld[32 * 64];      // [l][d] plain

  const int t  = threadIdx.x;
  const int bh = blockIdx.y;
  const size_t base = (size_t)bh * LEN * DD;
  const float* kb = kin + base;
  const float* vb = vin + base;
  const int l0 = blockIdx.x * 1024;

  // stage proj once (rows >= RR zeroed so pads contribute exactly 0)
  for (int idx = t; idx < RP * 16; idx += TB) {
    int r = idx >> 4, c4 = idx & 15;
    float4 val = make_float4(0.f, 0.f, 0.f, 0.f);
    if (r < RR) val = ((const float4*)proj)[idx];
    proj4[(r << 4) + (c4 ^ (r & 15))] = val;
  }

  float4 acc[17];
  float  ksacc[17];
#pragma unroll
  for (int i = 0; i < 17; ++i) { acc[i] = make_float4(0.f,0.f,0.f,0.f); ksacc[i] = 0.f; }

  const int rg = t & 15, lg = t >> 4;               // phase-2 map: one l, 17 r's
  const int tr = t & 15, td = (t >> 4) & 15, ls = t >> 8;  // phase-3 map

  __syncthreads();

  for (int s = 0; s < 32; ++s) {
    const int ls0 = l0 + s * 32;
    {   // stage K,V subtile: one float4 each (fully coalesced, 256B/16-lane group)
      int l = t >> 4, c4 = t & 15;
      float4 kvv = ((const float4*)(kb + (size_t)ls0 * DD))[t];
      float4 vvv = ((const float4*)(vb + (size_t)ls0 * DD))[t];
      k4[(l << 4) + (c4 ^ (l & 15))] = kvv;
      ((float4*)vld)[t] = vvv;
    }
    __syncthreads();

    // phase 2: features for 32 l-rows x 272 r  (each thread: 1 l, 17 r's)
    float f[17];
#pragma unroll
    for (int i = 0; i < 17; ++i) f[i] = 0.f;
#pragma unroll 4
    for (int c4 = 0; c4 < 16; ++c4) {
      float4 kk = k4[(lg << 4) + (c4 ^ (lg & 15))];
      const int sx = c4 ^ rg;   // r&15 == rg for all i
#pragma unroll
      for (int i = 0; i < 17; ++i) {
        float4 p4 = proj4[((rg + (i << 4)) << 4) + sx];
        f[i] += kk.x * p4.x + kk.y * p4.y + kk.z * p4.z + kk.w * p4.w;
      }
    }
#pragma unroll
    for (int i = 0; i < 17; ++i) {
      int r = rg + (i << 4);
      float fv = (r < RR) ? (fmaxf(f[i], 0.f) + EPSF) : 0.f;  // pads carry 0
      kp[lg * 273 + r] = fv;
      ksacc[i] += fv;
    }
    __syncthreads();

    // phase 3: KV outer-product accumulate (512 thr: 16 tr x 16 td x 2 l-halves)
#pragma unroll 4
    for (int lc = 0; lc < 16; ++lc) {
      int l = (ls << 4) + lc;
      float4 vv = ((const float4*)vld)[(l << 4) + td];   // 4-addr broadcast
#pragma unroll
      for (int i = 0; i < 17; ++i) {
        float kpv = kp[l * 273 + tr + (i << 4)];          // 16-addr broadcast
        acc[i].x += kpv * vv.x; acc[i].y += kpv * vv.y;
        acc[i].z += kpv * vv.z; acc[i].w += kpv * vv.w;
      }
    }
    __syncthreads();
  }

  // epilogue: both l-halves (ls=0/1) merge into kv_ws via atomics; 8 blocks/bh
  float* kvb = kv_ws + (size_t)bh * RP * DD;
#pragma unroll
  for (int i = 0; i < 17; ++i) {
    int r = tr + (i << 4);
    float* p = kvb + r * DD + (td << 2);
    atomicAdd(p + 0, acc[i].x);
    atomicAdd(p + 1, acc[i].y);
    atomicAdd(p + 2, acc[i].z);
    atomicAdd(p + 3, acc[i].w);
  }
  float* ksb = ksum_ws + bh * RP;
#pragma unroll
  for (int i = 0; i < 17; ++i) atomicAdd(ksb + rg + (i << 4), ksacc[i]);
}

// ---------------------------------------------------------------------------
// Kernel 2: per (bh, 64-row chunk): qp = relu(Q @ P^T)+eps into LDS (transposed),
//           then out = (qp @ KV) / (qp . ksum). proj LDS region reused for KV.
// LDS floats: proj 17408 | qp_t RP*68=18496 | q stage 2048 | ksum 272 = 38224 (152896 B)
// ---------------------------------------------------------------------------
__global__ __launch_bounds__(TB, 1) void perf_out_kernel(
    const float* __restrict__ qin, const float* __restrict__ proj,
    const float* __restrict__ kv_ws, const float* __restrict__ ksum_ws,
    float* __restrict__ out)
{
  __shared__ __align__(16) float smem[38224];
  float4* proj4    = (float4*)smem;                       // then reused as KV [RP][64]
  float*  qp_t     = smem + 17408;                        // [RP][68] (r-major, l-col)
  float4* q4s      = (float4*)(smem + 17408 + 18496);     // [32][16] swizzled
  float*  ksum_lds = smem + 17408 + 18496 + 2048;         // [RP]

  const int t  = threadIdx.x;
  const int bh = blockIdx.y;
  const int l0 = blockIdx.x * 64;
  const float* qb = qin + (size_t)bh * LEN * DD;

  for (int idx = t; idx < RP * 16; idx += TB) {
    int r = idx >> 4, c4 = idx & 15;
    float4 val = make_float4(0.f, 0.f, 0.f, 0.f);
    if (r < RR) val = ((const float4*)proj)[idx];
    proj4[(r << 4) + (c4 ^ (r & 15))] = val;
  }
  if (t < RP) ksum_lds[t] = ksum_ws[bh * RP + t];
  __syncthreads();

  const int rg = t & 15, lg = t >> 4;
  for (int s = 0; s < 2; ++s) {
    const int ls0 = l0 + s * 32;
    {
      int l = t >> 4, c4 = t & 15;
      float4 qv = ((const float4*)(qb + (size_t)ls0 * DD))[t];
      q4s[(l << 4) + (c4 ^ (l & 15))] = qv;
    }
    __syncthreads();
    float f[17];
#pragma unroll
    for (int i = 0; i < 17; ++i) f[i] = 0.f;
#pragma unroll 4
    for (int c4 = 0; c4 < 16; ++c4) {
      float4 qq = q4s[(lg << 4) + (c4 ^ (lg & 15))];
      const int sx = c4 ^ rg;
#pragma unroll
      for (int i = 0; i < 17; ++i) {
        float4 p4 = proj4[((rg + (i << 4)) << 4) + sx];
        f[i] += qq.x * p4.x + qq.y * p4.y + qq.z * p4.z + qq.w * p4.w;
      }
    }
    const int lcol = s * 32 + lg;
#pragma unroll
    for (int i = 0; i < 17; ++i) {
      int r = rg + (i << 4);
      float fv = (r < RR) ? (fmaxf(f[i], 0.f) + EPSF) : 0.f;
      qp_t[r * 68 + lcol] = fv;
    }
    __syncthreads();   // also fences last proj4 reads before KV overwrite below
  }

  // stage finished KV over the proj region
  float* kvl = smem;   // [RP][64]
  {
    const float4* kvg = (const float4*)(kv_ws + (size_t)bh * RP * DD);
    for (int idx = t; idx < RP * 16; idx += TB)
      ((float4*)kvl)[idx] = kvg[idx];
  }
  __syncthreads();

  // phase B: out[l][d] = sum_r qp[l][r]*KV[r][d];  den[l] = sum_r qp[l][r]*ksum[r]
  const int dq = t & 15;        // d = 4*dq (fast within 16-lane group -> coalesced)
  const int lq = t >> 4;        // rows l = 2*lq, 2*lq+1
  float4 o0 = make_float4(0.f,0.f,0.f,0.f), o1 = make_float4(0.f,0.f,0.f,0.f);
  float den0 = 0.f, den1 = 0.f;
#pragma unroll 4
  for (int r = 0; r < RP; ++r) {
    float2 q2  = *(const float2*)&qp_t[r * 68 + (lq << 1)];   // 4-addr broadcast
    float4 kv4 = *(const float4*)&kvl[(r << 6) + (dq << 2)];  // 2-way aliasing (free)
    float  ks  = ksum_lds[r];                                 // wave-uniform broadcast
    o0.x += q2.x * kv4.x; o0.y += q2.x * kv4.y; o0.z += q2.x * kv4.z; o0.w += q2.x * kv4.w;
    o1.x += q2.y * kv4.x; o1.y += q2.y * kv4.y; o1.z += q2.y * kv4.z; o1.w += q2.y * kv4.w;
    den0 += q2.x * ks;    den1 += q2.y * ks;
  }
  float inv0 = 1.f / den0, inv1 = 1.f / den1;
  o0.x *= inv0; o0.y *= inv0; o0.z *= inv0; o0.w *= inv0;
  o1.x *= inv1; o1.y *= inv1; o1.z *= inv1; o1.w *= inv1;
  size_t ob = ((size_t)bh * LEN + l0 + (lq << 1)) * DD + (dq << 2);
  *(float4*)(out + ob)      = o0;
  *(float4*)(out + ob + DD) = o1;
}

extern "C" void kernel_launch(void* const* d_in, const int* in_sizes, int n_in,
                              void* d_out, int out_size, void* d_ws, size_t ws_size,
                              hipStream_t stream) {
  (void)in_sizes; (void)n_in; (void)out_size; (void)ws_size;
  const float* q    = (const float*)d_in[0];
  const float* k    = (const float*)d_in[1];
  const float* v    = (const float*)d_in[2];
  const float* proj = (const float*)d_in[3];
  float* out     = (float*)d_out;
  float* kv_ws   = (float*)d_ws;                       // [32][272][64]
  float* ksum_ws = kv_ws + (size_t)BHC * RP * DD;      // [32][272]

  size_t zbytes = ((size_t)BHC * RP * DD + (size_t)BHC * RP) * sizeof(float);
  hipMemsetAsync(d_ws, 0, zbytes, stream);             // ws re-poisoned each launch

  perf_kv_kernel<<<dim3(8, BHC), dim3(TB), 0, stream>>>(k, v, proj, kv_ws, ksum_ws);
  perf_out_kernel<<<dim3(LEN / 64, BHC), dim3(TB), 0, stream>>>(q, proj, kv_ws, ksum_ws, out);
}